// Round 12
// baseline (434.107 us; speedup 1.0000x reference)
//
#include <hip/hip_runtime.h>

// ModulatedConv2d: B=16, C=512->512, 3x3 SAME, per-sample demodulated weights.
// R11 = R10 + drain removal (T3/T4 done right this time):
//  - sA3 double-buffered; A(p+1) issued AFTER the phase barrier (buf[p-1]
//    provably free) and waited with counted vmcnt(6) - never 0 in-loop.
//  - sX shrunk to K=32 (24KB, swizzle j^((p>>1)&3), 2-way=free) restaged per
//    (icb,hf) after the kx==2 compute+barrier; its completion folds into the
//    next phase's vmcnt(6). No full drain until the last phase.
//  - LDS 24+49.2=73.7KB -> 2 blocks/CU kept (R4's confound was losing a
//    block; R8 showed 2 vs 3 blocks is neutral).
// Model: MFMA floor 143us (19.4 cyc/MFMA/SIMD); R10's 280us = 48% MFMA-busy
// with ~50% lost to 48 serial vmcnt(0) drains. R10 FETCH fix (550->94MB)
// proved HBM is off the critical path; keep the XCD swizzle.

typedef __bf16 bf16x8 __attribute__((ext_vector_type(8)));
typedef float f32x4 __attribute__((ext_vector_type(4)));

__device__ __forceinline__ void async16(const void* g, void* s) {
  __builtin_amdgcn_global_load_lds((const __attribute__((address_space(1))) void*)g,
                                   (__attribute__((address_space(3))) void*)s, 16, 0, 0);
}

// style[b][i] = dot(w_embs[b,:], style_W[i,:]) + style_b[i] + 1
__global__ __launch_bounds__(256) void k_style(const float* __restrict__ we,
                                               const float* __restrict__ sW,
                                               const float* __restrict__ sb,
                                               float* __restrict__ style) {
  int lane = threadIdx.x & 63, wid = threadIdx.x >> 6;
  int b = blockIdx.x >> 7;
  int i = ((blockIdx.x & 127) << 2) + wid;
  const float* wer = we + b * 512;
  const float* swr = sW + i * 512;
  float acc = 0.f;
  for (int d = lane; d < 512; d += 64) acc += wer[d] * swr[d];
#pragma unroll
  for (int off = 32; off; off >>= 1) acc += __shfl_xor(acc, off);
  if (lane == 0) style[b * 512 + i] = acc + sb[i] + 1.0f;
}

// wsq[o][i] = sum_k cw[o][i][k]^2
__global__ __launch_bounds__(256) void k_wsq(const float* __restrict__ cw,
                                             float* __restrict__ wsq) {
  int t = blockIdx.x * 256 + threadIdx.x;  // o*512+i
  const float* p = cw + (long)t * 9;
  float s = 0.f;
#pragma unroll
  for (int k = 0; k < 9; ++k) s += p[k] * p[k];
  wsq[t] = s;
}

// rnorm[b][o] = rsqrt(sum_i style[b,i]^2 * wsq[o,i])
__global__ __launch_bounds__(256) void k_rnorm(const float* __restrict__ style,
                                               const float* __restrict__ wsq,
                                               float* __restrict__ rnorm) {
  int lane = threadIdx.x & 63, wid = threadIdx.x >> 6;
  int idx = blockIdx.x * 4 + wid;  // b*512 + o
  int b = idx >> 9, o = idx & 511;
  float acc = 0.f;
  for (int i = lane; i < 512; i += 64) {
    float s = style[(b << 9) + i];
    acc += s * s * wsq[(o << 9) + i];
  }
#pragma unroll
  for (int off = 32; off; off >>= 1) acc += __shfl_xor(acc, off);
  if (lane == 0) rnorm[idx] = rsqrtf(acc);
}

// wt[b][t'][o][i], t' = kx*3 + ky (kx-MAJOR): cw[o][i][ky*3+kx]*style*rnorm.
__global__ __launch_bounds__(256) void k_wt(const float* __restrict__ cw,
                                            const float* __restrict__ style,
                                            const float* __restrict__ rnorm,
                                            __bf16* __restrict__ wt) {
  int t = blockIdx.x * 256 + threadIdx.x;  // b*262144 + o*512 + i
  int b = t >> 18;
  int oi = t & 262143;
  int o = oi >> 9, i = oi & 511;
  float sc = style[(b << 9) + i] * rnorm[(b << 9) + o];
  const float* p = cw + (long)oi * 9;
#pragma unroll
  for (int k = 0; k < 9; ++k) {  // k = ky*3+kx  ->  t' = kx*3+ky
    int tp = (k % 3) * 3 + k / 3;
    wt[((long)(b * 9 + tp) << 18) + ((long)o << 9) + i] = (__bf16)(p[k] * sc);
  }
}

// xpad[b][r][c][i] (r,c in [0,66)) = bf16(imgs[b][i][r-1][c-1]), zero border.
__global__ __launch_bounds__(256) void k_xpad(const float* __restrict__ imgs,
                                              __bf16* __restrict__ xpad) {
  int t = blockIdx.x * 256 + threadIdx.x;  // b*4356 + r*66 + c
  if (t >= 16 * 4356) return;
  int b = t / 4356;
  int rc = t - b * 4356;
  int r = rc / 66, c = rc - (rc / 66) * 66;
  __bf16* dst = xpad + (long)t * 512;
  if (r == 0 || r == 65 || c == 0 || c == 65) {
    const f32x4 z = {0.f, 0.f, 0.f, 0.f};
#pragma unroll 4
    for (int j = 0; j < 64; ++j) *(f32x4*)(dst + j * 8) = z;
  } else {
    const float* src = imgs + ((long)b << 21) + ((r - 1) << 6) + (c - 1);
    for (int j = 0; j < 64; ++j) {
      bf16x8 v;
#pragma unroll
      for (int q = 0; q < 8; ++q) v[q] = (__bf16)src[(long)(j * 8 + q) << 12];
      *(bf16x8*)(dst + j * 8) = v;
    }
  }
}

// Conv: block = 128 o x 256 px (8h x 32w), 4 waves = 2(o) x 2(px), wave
// tile 64o x 128px, acc[4][8]. Phase = (icb,hf,kx) (48 total):
//   barrier -> issue A(p+1) into buf^1 -> vmcnt(6) -> 96 MFMA
//   [kx==2: barrier -> issue X(next icb,hf)]
// sX: 340px x 32ch = 1536 slots x 16B (24KB), swizzle j^((p>>1)&3).
// sA3: 2 x (3 taps x 128o x 32ch) = 49.2KB. Total 73.7KB -> 2 blocks/CU.
__global__ __launch_bounds__(256, 2) void k_conv(const __bf16* __restrict__ xpad,
                                                 const __bf16* __restrict__ wt,
                                                 const float* __restrict__ bias,
                                                 float* __restrict__ out) {
  __shared__ __attribute__((aligned(16))) __bf16 sX[1536 * 8];       // 24576 B
  __shared__ __attribute__((aligned(16))) __bf16 sA3[2 * 3 * 128 * 32]; // 49152 B

  const int tid = threadIdx.x;
  const int lane = tid & 63;
  const int wid = tid >> 6;
  const int wr = wid >> 1, wp = wid & 1;
  const int l15 = lane & 15, lq = lane >> 4;

  // T1 XCD-chunked swizzle (R10: FETCH 550->94MB). Grid 1024 = 8 x 128.
  const int bid0 = blockIdx.x;
  const int bid = ((bid0 & 7) << 7) | (bid0 >> 3);

  const int b = bid >> 6;          // 64 blocks / batch
  const int r6 = bid & 63;
  const int o0 = (r6 >> 4) << 7;   // 4 o-tiles of 128
  const int st = r6 & 15;          // 16 spatial tiles
  const int h0 = (st >> 1) << 3;   // 8 h-tiles * 8 rows
  const int w0 = (st & 1) << 5;    // 2 w-tiles * 32 cols
  const int b66 = b * 66;

  // X staging (K=32): slot s=it*256+tid (clamp 1359), px p=s>>2, holds
  // chunk j=(s&3)^((p>>1)&3); slots 1360..1535 = dup pad, never read.
  const __bf16* xg[6];
#pragma unroll
  for (int it = 0; it < 6; ++it) {
    int s = it * 256 + tid;
    if (s > 1359) s = 1359;
    int p = s >> 2;
    int j = (s & 3) ^ ((p >> 1) & 3);
    int lr = p / 34, lc = p - (p / 34) * 34;
    xg[it] = xpad + ((long)((b66 + h0 + lr) * 66) + (w0 + lc)) * 512 + j * 8;
  }
  // A staging (R8/R10-verbatim K=32 slab): it 0..5: tap=it>>1, rowgrp=it&1.
  const int abase = ((o0 + (tid >> 2)) << 9) + (((tid & 3) ^ ((tid >> 3) & 3)) << 3);
  const __bf16* wtb = wt + (long)b * 2359296;

  f32x4 acc[4][8];
  const f32x4 zero4 = {0.f, 0.f, 0.f, 0.f};
#pragma unroll
  for (int m = 0; m < 4; ++m)
#pragma unroll
    for (int n = 0; n < 8; ++n) acc[m][n] = zero4;

  const int arowbase = (wr << 6) + l15;          // A o-row for m=0
  const int csA = (lq ^ ((l15 >> 1) & 3)) << 3;  // A chunk swizzle (elems)
  const int rbase = wp << 2;                     // wave's first halo row

  // ---- prologue: issue X(icb0,hf0) + A(phase0)->buf0; no drain needed
  // (phase0's vmcnt(6) waits these 12, leaving only A(phase1) in flight).
#pragma unroll
  for (int it = 0; it < 6; ++it)
    async16(xg[it], (char*)sX + it * 4096 + (wid << 10));
#pragma unroll
  for (int it = 0; it < 6; ++it)
    async16(wtb + abase + (it >> 1) * 262144 + (it & 1) * 32768,
            (char*)sA3 + it * 4096 + (wid << 10));

  for (int icb = 0; icb < 8; ++icb) {
#pragma unroll
    for (int hf = 0; hf < 2; ++hf) {
#pragma unroll
      for (int kx = 0; kx < 3; ++kx) {
        const int bufc = (3 * hf + kx) & 1;  // phase parity (icb*6 is even)
        __builtin_amdgcn_sched_barrier(0);
        __builtin_amdgcn_s_barrier();  // all waves done phase p-1 -> buf^1 free
        const bool last = (icb == 7) && (hf == 1) && (kx == 2);
        if (!last) {
          const int nkx = (kx == 2) ? 0 : kx + 1;
          const int nhf = (kx == 2) ? (hf ^ 1) : hf;
          const int nicb = icb + ((kx == 2 && hf == 1) ? 1 : 0);
          const __bf16* wa = wtb + abase + (nicb << 6) + (nhf << 5);
          char* dst = (char*)sA3 + ((bufc ^ 1) * 24576) + (wid << 10);
#pragma unroll
          for (int it = 0; it < 6; ++it)
            async16(wa + (nkx * 3 + (it >> 1)) * 262144 + (it & 1) * 32768,
                    dst + it * 4096);
        }
        if (last) {
          asm volatile("s_waitcnt vmcnt(0)" ::: "memory");
        } else {
          asm volatile("s_waitcnt vmcnt(6)" ::: "memory");  // A(p) [+X] done
        }
        __builtin_amdgcn_sched_barrier(0);
        // ---- compute: 96 MFMA from sA3[bufc] + sX ----
        bf16x8 bfr[6][2];
#pragma unroll
        for (int r = 0; r < 6; ++r)
#pragma unroll
          for (int c = 0; c < 2; ++c) {
            int p = (rbase + r) * 34 + (c << 4) + l15 + kx;
            bfr[r][c] = *(const bf16x8*)&sX[(p << 5) + ((lq ^ ((p >> 1) & 3)) << 3)];
          }
#pragma unroll
        for (int ky = 0; ky < 3; ++ky) {
          const __bf16* sAb = sA3 + bufc * 12288 + ky * 4096;
          bf16x8 af[4];
#pragma unroll
          for (int m = 0; m < 4; ++m)
            af[m] = *(const bf16x8*)&sAb[((arowbase + (m << 4)) << 5) + csA];
#pragma unroll
          for (int m = 0; m < 4; ++m)
#pragma unroll
            for (int n = 0; n < 8; ++n)
              acc[m][n] = __builtin_amdgcn_mfma_f32_16x16x32_bf16(
                  af[m], bfr[(n >> 1) + ky][n & 1], acc[m][n], 0, 0, 0);
        }
        // ---- hf boundary: restage sX for next (icb,hf) after all reads ----
        if (kx == 2 && !last) {
          __builtin_amdgcn_sched_barrier(0);
          __builtin_amdgcn_s_barrier();  // all waves done reading sX
          const int chX = ((icb + hf) << 6) + ((hf ^ 1) << 5);
#pragma unroll
          for (int it = 0; it < 6; ++it)
            async16(xg[it] + chX, (char*)sX + it * 4096 + (wid << 10));
        }
      }
    }
  }

  // Epilogue: C/D col=lane&15 (pixel), row=(lane>>4)*4+q (out chan).
  float* outb = out + ((long)b << 21);
#pragma unroll
  for (int m = 0; m < 4; ++m) {
    int ob = o0 + (wr << 6) + (m << 4) + (lq << 2);
#pragma unroll
    for (int n = 0; n < 8; ++n) {
      int pid = (wp << 7) + (n << 4) + l15;
      int h = h0 + (pid >> 5), w = w0 + (pid & 31);
#pragma unroll
      for (int q = 0; q < 4; ++q) {
        int o = ob + q;
        outb[((long)o << 12) + (h << 6) + w] = acc[m][n][q] + bias[o];
      }
    }
  }
}

extern "C" void kernel_launch(void* const* d_in, const int* in_sizes, int n_in,
                              void* d_out, int out_size, void* d_ws, size_t ws_size,
                              hipStream_t stream) {
  const float* imgs = (const float*)d_in[0];
  const float* w_embs = (const float*)d_in[1];
  const float* cw = (const float*)d_in[2];
  const float* bias = (const float*)d_in[3];
  const float* style_W = (const float*)d_in[4];
  const float* style_b = (const float*)d_in[5];
  float* out = (float*)d_out;

  char* ws = (char*)d_ws;
  float* style = (float*)(ws);                          // 32 KB
  float* rnorm = (float*)(ws + (32 << 10));             // 32 KB
  float* wsq = (float*)(ws + (64 << 10));               // 1 MB
  __bf16* wt = (__bf16*)(ws + (64 << 10) + (1 << 20));  // 75,497,472 B
  __bf16* xpad = (__bf16*)(ws + (64 << 10) + (1 << 20) + 75497472);  // 71,368,704 B
  size_t need = (size_t)(64 << 10) + (1 << 20) + 75497472ull + 71368704ull;
  if (ws_size < need) return;  // leaves d_out poisoned -> visible failure mode

  k_style<<<2048, 256, 0, stream>>>(w_embs, style_W, style_b, style);
  k_wsq<<<1024, 256, 0, stream>>>(cw, wsq);
  k_rnorm<<<2048, 256, 0, stream>>>(style, wsq, rnorm);
  k_wt<<<16384, 256, 0, stream>>>(cw, style, rnorm, wt);
  k_xpad<<<273, 256, 0, stream>>>(imgs, xpad);
  k_conv<<<1024, 256, 0, stream>>>(xpad, wt, bias, out);
}

// Round 13
// 371.687 us; speedup vs baseline: 1.1679x; 1.1679x over previous
//
#include <hip/hip_runtime.h>

// ModulatedConv2d: B=16, C=512->512, 3x3 SAME, per-sample demodulated weights.
// R12 = R10 byte-identical revert + T5 setprio around the MFMA cluster.
// R11 post-mortem: counted-vmcnt dbuf lost 3rd time (VGPR+AGPR=256 at the
// 2-wave cap -> no scheduler headroom; block desync broke A-slab L2 sharing
// [FETCH 94->185MB]; sched_barrier spam = m141). Lockstep drains are partly
// load-bearing (L2 temporal locality). R10 audit: phase-slot 7000cyc =
// 3725 MFMA + ~2300 LDS + ~1100 VALU + drain; all other catalog levers
// measured null/negative on this op. T5 is the last cheap untested lever:
// 2 independent block groups per CU = wave role diversity precondition.

typedef __bf16 bf16x8 __attribute__((ext_vector_type(8)));
typedef float f32x4 __attribute__((ext_vector_type(4)));

__device__ __forceinline__ void async16(const void* g, void* s) {
  __builtin_amdgcn_global_load_lds((const __attribute__((address_space(1))) void*)g,
                                   (__attribute__((address_space(3))) void*)s, 16, 0, 0);
}

// style[b][i] = dot(w_embs[b,:], style_W[i,:]) + style_b[i] + 1
__global__ __launch_bounds__(256) void k_style(const float* __restrict__ we,
                                               const float* __restrict__ sW,
                                               const float* __restrict__ sb,
                                               float* __restrict__ style) {
  int lane = threadIdx.x & 63, wid = threadIdx.x >> 6;
  int b = blockIdx.x >> 7;
  int i = ((blockIdx.x & 127) << 2) + wid;
  const float* wer = we + b * 512;
  const float* swr = sW + i * 512;
  float acc = 0.f;
  for (int d = lane; d < 512; d += 64) acc += wer[d] * swr[d];
#pragma unroll
  for (int off = 32; off; off >>= 1) acc += __shfl_xor(acc, off);
  if (lane == 0) style[b * 512 + i] = acc + sb[i] + 1.0f;
}

// wsq[o][i] = sum_k cw[o][i][k]^2
__global__ __launch_bounds__(256) void k_wsq(const float* __restrict__ cw,
                                             float* __restrict__ wsq) {
  int t = blockIdx.x * 256 + threadIdx.x;  // o*512+i
  const float* p = cw + (long)t * 9;
  float s = 0.f;
#pragma unroll
  for (int k = 0; k < 9; ++k) s += p[k] * p[k];
  wsq[t] = s;
}

// rnorm[b][o] = rsqrt(sum_i style[b,i]^2 * wsq[o,i])
__global__ __launch_bounds__(256) void k_rnorm(const float* __restrict__ style,
                                               const float* __restrict__ wsq,
                                               float* __restrict__ rnorm) {
  int lane = threadIdx.x & 63, wid = threadIdx.x >> 6;
  int idx = blockIdx.x * 4 + wid;  // b*512 + o
  int b = idx >> 9, o = idx & 511;
  float acc = 0.f;
  for (int i = lane; i < 512; i += 64) {
    float s = style[(b << 9) + i];
    acc += s * s * wsq[(o << 9) + i];
  }
#pragma unroll
  for (int off = 32; off; off >>= 1) acc += __shfl_xor(acc, off);
  if (lane == 0) rnorm[idx] = rsqrtf(acc);
}

// wt[b][t'][o][i], t' = kx*3 + ky (kx-MAJOR so a (ky=0..2,kx) slab is
// contiguous): value = cw[o][i][ky*3+kx] * style[b][i] * rnorm[b][o].
__global__ __launch_bounds__(256) void k_wt(const float* __restrict__ cw,
                                            const float* __restrict__ style,
                                            const float* __restrict__ rnorm,
                                            __bf16* __restrict__ wt) {
  int t = blockIdx.x * 256 + threadIdx.x;  // b*262144 + o*512 + i
  int b = t >> 18;
  int oi = t & 262143;
  int o = oi >> 9, i = oi & 511;
  float sc = style[(b << 9) + i] * rnorm[(b << 9) + o];
  const float* p = cw + (long)oi * 9;
#pragma unroll
  for (int k = 0; k < 9; ++k) {  // k = ky*3+kx  ->  t' = kx*3+ky
    int tp = (k % 3) * 3 + k / 3;
    wt[((long)(b * 9 + tp) << 18) + ((long)o << 9) + i] = (__bf16)(p[k] * sc);
  }
}

// xpad[b][r][c][i] (r,c in [0,66)) = bf16(imgs[b][i][r-1][c-1]), zero border.
__global__ __launch_bounds__(256) void k_xpad(const float* __restrict__ imgs,
                                              __bf16* __restrict__ xpad) {
  int t = blockIdx.x * 256 + threadIdx.x;  // b*4356 + r*66 + c
  if (t >= 16 * 4356) return;
  int b = t / 4356;
  int rc = t - b * 4356;
  int r = rc / 66, c = rc - (rc / 66) * 66;
  __bf16* dst = xpad + (long)t * 512;
  if (r == 0 || r == 65 || c == 0 || c == 65) {
    const f32x4 z = {0.f, 0.f, 0.f, 0.f};
#pragma unroll 4
    for (int j = 0; j < 64; ++j) *(f32x4*)(dst + j * 8) = z;
  } else {
    const float* src = imgs + ((long)b << 21) + ((r - 1) << 6) + (c - 1);
    for (int j = 0; j < 64; ++j) {
      bf16x8 v;
#pragma unroll
      for (int q = 0; q < 8; ++q) v[q] = (__bf16)src[(long)(j * 8 + q) << 12];
      *(bf16x8*)(dst + j * 8) = v;
    }
  }
}

// Conv: block = 128 o x 256 px (8h x 32w), 4 waves = 2(o) x 2(px), wave
// tile 64o x 128px, acc[4][8]. Phase = (icb64, hf, kx): stage 3-tap x 32ch
// A-slab (24.6KB) [+ X(340px,K=64) at first phase of icb]; compute
// bfr[6][2] once, sweep ky=0..2 with af[4] -> 96 MFMA/phase/wave.
// LDS: sX 45056 + sA3 24576 = 69632 B -> 2 blocks/CU.
__global__ __launch_bounds__(256, 2) void k_conv(const __bf16* __restrict__ xpad,
                                                 const __bf16* __restrict__ wt,
                                                 const float* __restrict__ bias,
                                                 float* __restrict__ out) {
  __shared__ __attribute__((aligned(16))) __bf16 sX[2816 * 8];      // 340 px used
  __shared__ __attribute__((aligned(16))) __bf16 sA3[3 * 128 * 32]; // 3-tap K=32

  const int tid = threadIdx.x;
  const int lane = tid & 63;
  const int wid = tid >> 6;
  const int wr = wid >> 1, wp = wid & 1;
  const int l15 = lane & 15, lq = lane >> 4;

  // T1 XCD-chunked swizzle (R10: FETCH 550->94MB). Grid 1024 = 8 x 128.
  const int bid0 = blockIdx.x;
  const int bid = ((bid0 & 7) << 7) | (bid0 >> 3);

  const int b = bid >> 6;          // 64 blocks / batch
  const int r6 = bid & 63;
  const int o0 = (r6 >> 4) << 7;   // 4 o-tiles of 128
  const int st = r6 & 15;          // 16 spatial tiles
  const int h0 = (st >> 1) << 3;   // 8 h-tiles * 8 rows
  const int w0 = (st & 1) << 5;    // 2 w-tiles * 32 cols
  const int b66 = b * 66;

  // X staging (R3-proven 340px geometry): slot s=it*256+tid (clamped 2719),
  // px p=s>>3, holds chunk j=(s&7)^(p&7); LDS pad slots 2720..2815 unused.
  const __bf16* xg[11];
#pragma unroll
  for (int it = 0; it < 11; ++it) {
    int s = it * 256 + tid;
    if (s > 2719) s = 2719;
    int p = s >> 3;
    int j = (s & 7) ^ (p & 7);
    int lr = p / 34, lc = p - (p / 34) * 34;
    xg[it] = xpad + ((long)((b66 + h0 + lr) * 66) + (w0 + lc)) * 512 + j * 8;
  }
  // A staging (R8-verbatim K=32 slab): it 0..5: tap=it>>1, rowgrp=it&1.
  const int abase = ((o0 + (tid >> 2)) << 9) + (((tid & 3) ^ ((tid >> 3) & 3)) << 3);
  const __bf16* wtb = wt + (long)b * 2359296;

  f32x4 acc[4][8];
  const f32x4 zero4 = {0.f, 0.f, 0.f, 0.f};
#pragma unroll
  for (int m = 0; m < 4; ++m)
#pragma unroll
    for (int n = 0; n < 8; ++n) acc[m][n] = zero4;

  const int arowbase = (wr << 6) + l15;          // A o-row for m=0
  const int csA = (lq ^ ((l15 >> 1) & 3)) << 3;  // A chunk swizzle (elems)
  const int rbase = wp << 2;                     // wave's first halo row

  bool first = true;
  for (int icb = 0; icb < 8; ++icb) {
    const int ic = icb << 6;
#pragma unroll
    for (int hf = 0; hf < 2; ++hf) {
#pragma unroll
      for (int kx = 0; kx < 3; ++kx) {
        if (!first) __syncthreads();  // prior compute done; safe to overwrite
        first = false;
        if (hf == 0 && kx == 0) {
#pragma unroll
          for (int it = 0; it < 11; ++it)
            async16(xg[it] + ic, (char*)sX + it * 4096 + (wid << 10));
        }
        {
          const __bf16* wa = wtb + abase + ic + (hf << 5);
#pragma unroll
          for (int it = 0; it < 6; ++it)
            async16(wa + (kx * 3 + (it >> 1)) * 262144 + (it & 1) * 32768,
                    (char*)sA3 + it * 4096 + (wid << 10));
        }
        __syncthreads();  // compiler drains vmcnt(0) before s_barrier
        // ---- compute: 96 MFMA from sA3 + sX (T5: prefer this wave) ----
        __builtin_amdgcn_s_setprio(1);
        const int jb = (hf << 2) | lq;  // sX chunk for this half
        bf16x8 bfr[6][2];
#pragma unroll
        for (int r = 0; r < 6; ++r)
#pragma unroll
          for (int c = 0; c < 2; ++c) {
            int p = (rbase + r) * 34 + (c << 4) + l15 + kx;
            bfr[r][c] = *(const bf16x8*)&sX[(p << 6) + ((jb ^ (p & 7)) << 3)];
          }
#pragma unroll
        for (int ky = 0; ky < 3; ++ky) {
          const __bf16* sAb = sA3 + ky * 4096;
          bf16x8 af[4];
#pragma unroll
          for (int m = 0; m < 4; ++m)
            af[m] = *(const bf16x8*)&sAb[((arowbase + (m << 4)) << 5) + csA];
#pragma unroll
          for (int m = 0; m < 4; ++m)
#pragma unroll
            for (int n = 0; n < 8; ++n)
              acc[m][n] = __builtin_amdgcn_mfma_f32_16x16x32_bf16(
                  af[m], bfr[(n >> 1) + ky][n & 1], acc[m][n], 0, 0, 0);
        }
        __builtin_amdgcn_s_setprio(0);
      }
    }
  }

  // Epilogue: C/D col=lane&15 (pixel), row=(lane>>4)*4+q (out chan).
  // pixel id = wp*128 + n*16 + l15 -> h = h0 + pid>>5, w = w0 + (pid&31).
  float* outb = out + ((long)b << 21);
#pragma unroll
  for (int m = 0; m < 4; ++m) {
    int ob = o0 + (wr << 6) + (m << 4) + (lq << 2);
#pragma unroll
    for (int n = 0; n < 8; ++n) {
      int pid = (wp << 7) + (n << 4) + l15;
      int h = h0 + (pid >> 5), w = w0 + (pid & 31);
#pragma unroll
      for (int q = 0; q < 4; ++q) {
        int o = ob + q;
        outb[((long)o << 12) + (h << 6) + w] = acc[m][n][q] + bias[o];
      }
    }
  }
}

extern "C" void kernel_launch(void* const* d_in, const int* in_sizes, int n_in,
                              void* d_out, int out_size, void* d_ws, size_t ws_size,
                              hipStream_t stream) {
  const float* imgs = (const float*)d_in[0];
  const float* w_embs = (const float*)d_in[1];
  const float* cw = (const float*)d_in[2];
  const float* bias = (const float*)d_in[3];
  const float* style_W = (const float*)d_in[4];
  const float* style_b = (const float*)d_in[5];
  float* out = (float*)d_out;

  char* ws = (char*)d_ws;
  float* style = (float*)(ws);                          // 32 KB
  float* rnorm = (float*)(ws + (32 << 10));             // 32 KB
  float* wsq = (float*)(ws + (64 << 10));               // 1 MB
  __bf16* wt = (__bf16*)(ws + (64 << 10) + (1 << 20));  // 75,497,472 B
  __bf16* xpad = (__bf16*)(ws + (64 << 10) + (1 << 20) + 75497472);  // 71,368,704 B
  size_t need = (size_t)(64 << 10) + (1 << 20) + 75497472ull + 71368704ull;
  if (ws_size < need) return;  // leaves d_out poisoned -> visible failure mode

  k_style<<<2048, 256, 0, stream>>>(w_embs, style_W, style_b, style);
  k_wsq<<<1024, 256, 0, stream>>>(cw, wsq);
  k_rnorm<<<2048, 256, 0, stream>>>(style, wsq, rnorm);
  k_wt<<<16384, 256, 0, stream>>>(cw, style, rnorm, wt);
  k_xpad<<<273, 256, 0, stream>>>(imgs, xpad);
  k_conv<<<1024, 256, 0, stream>>>(xpad, wt, bias, out);
}

// Round 14
// 371.506 us; speedup vs baseline: 1.1685x; 1.0005x over previous
//
#include <hip/hip_runtime.h>

// ModulatedConv2d: B=16, C=512->512, 3x3 SAME, per-sample demodulated weights.
// R12 = R10 byte-identical revert + T5 setprio around the MFMA cluster.
// R11 post-mortem: counted-vmcnt dbuf lost 3rd time (VGPR+AGPR=256 at the
// 2-wave cap -> no scheduler headroom; block desync broke A-slab L2 sharing
// [FETCH 94->185MB]; sched_barrier spam = m141). Lockstep drains are partly
// load-bearing (L2 temporal locality). R10 audit: phase-slot 7000cyc =
// 3725 MFMA + ~2300 LDS + ~1100 VALU + drain; all other catalog levers
// measured null/negative on this op. T5 is the last cheap untested lever:
// 2 independent block groups per CU = wave role diversity precondition.

typedef __bf16 bf16x8 __attribute__((ext_vector_type(8)));
typedef float f32x4 __attribute__((ext_vector_type(4)));

__device__ __forceinline__ void async16(const void* g, void* s) {
  __builtin_amdgcn_global_load_lds((const __attribute__((address_space(1))) void*)g,
                                   (__attribute__((address_space(3))) void*)s, 16, 0, 0);
}

// style[b][i] = dot(w_embs[b,:], style_W[i,:]) + style_b[i] + 1
__global__ __launch_bounds__(256) void k_style(const float* __restrict__ we,
                                               const float* __restrict__ sW,
                                               const float* __restrict__ sb,
                                               float* __restrict__ style) {
  int lane = threadIdx.x & 63, wid = threadIdx.x >> 6;
  int b = blockIdx.x >> 7;
  int i = ((blockIdx.x & 127) << 2) + wid;
  const float* wer = we + b * 512;
  const float* swr = sW + i * 512;
  float acc = 0.f;
  for (int d = lane; d < 512; d += 64) acc += wer[d] * swr[d];
#pragma unroll
  for (int off = 32; off; off >>= 1) acc += __shfl_xor(acc, off);
  if (lane == 0) style[b * 512 + i] = acc + sb[i] + 1.0f;
}

// wsq[o][i] = sum_k cw[o][i][k]^2
__global__ __launch_bounds__(256) void k_wsq(const float* __restrict__ cw,
                                             float* __restrict__ wsq) {
  int t = blockIdx.x * 256 + threadIdx.x;  // o*512+i
  const float* p = cw + (long)t * 9;
  float s = 0.f;
#pragma unroll
  for (int k = 0; k < 9; ++k) s += p[k] * p[k];
  wsq[t] = s;
}

// rnorm[b][o] = rsqrt(sum_i style[b,i]^2 * wsq[o,i])
__global__ __launch_bounds__(256) void k_rnorm(const float* __restrict__ style,
                                               const float* __restrict__ wsq,
                                               float* __restrict__ rnorm) {
  int lane = threadIdx.x & 63, wid = threadIdx.x >> 6;
  int idx = blockIdx.x * 4 + wid;  // b*512 + o
  int b = idx >> 9, o = idx & 511;
  float acc = 0.f;
  for (int i = lane; i < 512; i += 64) {
    float s = style[(b << 9) + i];
    acc += s * s * wsq[(o << 9) + i];
  }
#pragma unroll
  for (int off = 32; off; off >>= 1) acc += __shfl_xor(acc, off);
  if (lane == 0) rnorm[idx] = rsqrtf(acc);
}

// wt[b][t'][o][i], t' = kx*3 + ky (kx-MAJOR so a (ky=0..2,kx) slab is
// contiguous): value = cw[o][i][ky*3+kx] * style[b][i] * rnorm[b][o].
__global__ __launch_bounds__(256) void k_wt(const float* __restrict__ cw,
                                            const float* __restrict__ style,
                                            const float* __restrict__ rnorm,
                                            __bf16* __restrict__ wt) {
  int t = blockIdx.x * 256 + threadIdx.x;  // b*262144 + o*512 + i
  int b = t >> 18;
  int oi = t & 262143;
  int o = oi >> 9, i = oi & 511;
  float sc = style[(b << 9) + i] * rnorm[(b << 9) + o];
  const float* p = cw + (long)oi * 9;
#pragma unroll
  for (int k = 0; k < 9; ++k) {  // k = ky*3+kx  ->  t' = kx*3+ky
    int tp = (k % 3) * 3 + k / 3;
    wt[((long)(b * 9 + tp) << 18) + ((long)o << 9) + i] = (__bf16)(p[k] * sc);
  }
}

// xpad[b][r][c][i] (r,c in [0,66)) = bf16(imgs[b][i][r-1][c-1]), zero border.
__global__ __launch_bounds__(256) void k_xpad(const float* __restrict__ imgs,
                                              __bf16* __restrict__ xpad) {
  int t = blockIdx.x * 256 + threadIdx.x;  // b*4356 + r*66 + c
  if (t >= 16 * 4356) return;
  int b = t / 4356;
  int rc = t - b * 4356;
  int r = rc / 66, c = rc - (rc / 66) * 66;
  __bf16* dst = xpad + (long)t * 512;
  if (r == 0 || r == 65 || c == 0 || c == 65) {
    const f32x4 z = {0.f, 0.f, 0.f, 0.f};
#pragma unroll 4
    for (int j = 0; j < 64; ++j) *(f32x4*)(dst + j * 8) = z;
  } else {
    const float* src = imgs + ((long)b << 21) + ((r - 1) << 6) + (c - 1);
    for (int j = 0; j < 64; ++j) {
      bf16x8 v;
#pragma unroll
      for (int q = 0; q < 8; ++q) v[q] = (__bf16)src[(long)(j * 8 + q) << 12];
      *(bf16x8*)(dst + j * 8) = v;
    }
  }
}

// Conv: block = 128 o x 256 px (8h x 32w), 4 waves = 2(o) x 2(px), wave
// tile 64o x 128px, acc[4][8]. Phase = (icb64, hf, kx): stage 3-tap x 32ch
// A-slab (24.6KB) [+ X(340px,K=64) at first phase of icb]; compute
// bfr[6][2] once, sweep ky=0..2 with af[4] -> 96 MFMA/phase/wave.
// LDS: sX 45056 + sA3 24576 = 69632 B -> 2 blocks/CU.
__global__ __launch_bounds__(256, 2) void k_conv(const __bf16* __restrict__ xpad,
                                                 const __bf16* __restrict__ wt,
                                                 const float* __restrict__ bias,
                                                 float* __restrict__ out) {
  __shared__ __attribute__((aligned(16))) __bf16 sX[2816 * 8];      // 340 px used
  __shared__ __attribute__((aligned(16))) __bf16 sA3[3 * 128 * 32]; // 3-tap K=32

  const int tid = threadIdx.x;
  const int lane = tid & 63;
  const int wid = tid >> 6;
  const int wr = wid >> 1, wp = wid & 1;
  const int l15 = lane & 15, lq = lane >> 4;

  // T1 XCD-chunked swizzle (R10: FETCH 550->94MB). Grid 1024 = 8 x 128.
  const int bid0 = blockIdx.x;
  const int bid = ((bid0 & 7) << 7) | (bid0 >> 3);

  const int b = bid >> 6;          // 64 blocks / batch
  const int r6 = bid & 63;
  const int o0 = (r6 >> 4) << 7;   // 4 o-tiles of 128
  const int st = r6 & 15;          // 16 spatial tiles
  const int h0 = (st >> 1) << 3;   // 8 h-tiles * 8 rows
  const int w0 = (st & 1) << 5;    // 2 w-tiles * 32 cols
  const int b66 = b * 66;

  // X staging (R3-proven 340px geometry): slot s=it*256+tid (clamped 2719),
  // px p=s>>3, holds chunk j=(s&7)^(p&7); LDS pad slots 2720..2815 unused.
  const __bf16* xg[11];
#pragma unroll
  for (int it = 0; it < 11; ++it) {
    int s = it * 256 + tid;
    if (s > 2719) s = 2719;
    int p = s >> 3;
    int j = (s & 7) ^ (p & 7);
    int lr = p / 34, lc = p - (p / 34) * 34;
    xg[it] = xpad + ((long)((b66 + h0 + lr) * 66) + (w0 + lc)) * 512 + j * 8;
  }
  // A staging (R8-verbatim K=32 slab): it 0..5: tap=it>>1, rowgrp=it&1.
  const int abase = ((o0 + (tid >> 2)) << 9) + (((tid & 3) ^ ((tid >> 3) & 3)) << 3);
  const __bf16* wtb = wt + (long)b * 2359296;

  f32x4 acc[4][8];
  const f32x4 zero4 = {0.f, 0.f, 0.f, 0.f};
#pragma unroll
  for (int m = 0; m < 4; ++m)
#pragma unroll
    for (int n = 0; n < 8; ++n) acc[m][n] = zero4;

  const int arowbase = (wr << 6) + l15;          // A o-row for m=0
  const int csA = (lq ^ ((l15 >> 1) & 3)) << 3;  // A chunk swizzle (elems)
  const int rbase = wp << 2;                     // wave's first halo row

  bool first = true;
  for (int icb = 0; icb < 8; ++icb) {
    const int ic = icb << 6;
#pragma unroll
    for (int hf = 0; hf < 2; ++hf) {
#pragma unroll
      for (int kx = 0; kx < 3; ++kx) {
        if (!first) __syncthreads();  // prior compute done; safe to overwrite
        first = false;
        if (hf == 0 && kx == 0) {
#pragma unroll
          for (int it = 0; it < 11; ++it)
            async16(xg[it] + ic, (char*)sX + it * 4096 + (wid << 10));
        }
        {
          const __bf16* wa = wtb + abase + ic + (hf << 5);
#pragma unroll
          for (int it = 0; it < 6; ++it)
            async16(wa + (kx * 3 + (it >> 1)) * 262144 + (it & 1) * 32768,
                    (char*)sA3 + it * 4096 + (wid << 10));
        }
        __syncthreads();  // compiler drains vmcnt(0) before s_barrier
        // ---- compute: 96 MFMA from sA3 + sX (T5: prefer this wave) ----
        __builtin_amdgcn_s_setprio(1);
        const int jb = (hf << 2) | lq;  // sX chunk for this half
        bf16x8 bfr[6][2];
#pragma unroll
        for (int r = 0; r < 6; ++r)
#pragma unroll
          for (int c = 0; c < 2; ++c) {
            int p = (rbase + r) * 34 + (c << 4) + l15 + kx;
            bfr[r][c] = *(const bf16x8*)&sX[(p << 6) + ((jb ^ (p & 7)) << 3)];
          }
#pragma unroll
        for (int ky = 0; ky < 3; ++ky) {
          const __bf16* sAb = sA3 + ky * 4096;
          bf16x8 af[4];
#pragma unroll
          for (int m = 0; m < 4; ++m)
            af[m] = *(const bf16x8*)&sAb[((arowbase + (m << 4)) << 5) + csA];
#pragma unroll
          for (int m = 0; m < 4; ++m)
#pragma unroll
            for (int n = 0; n < 8; ++n)
              acc[m][n] = __builtin_amdgcn_mfma_f32_16x16x32_bf16(
                  af[m], bfr[(n >> 1) + ky][n & 1], acc[m][n], 0, 0, 0);
        }
        __builtin_amdgcn_s_setprio(0);
      }
    }
  }

  // Epilogue: C/D col=lane&15 (pixel), row=(lane>>4)*4+q (out chan).
  // pixel id = wp*128 + n*16 + l15 -> h = h0 + pid>>5, w = w0 + (pid&31).
  float* outb = out + ((long)b << 21);
#pragma unroll
  for (int m = 0; m < 4; ++m) {
    int ob = o0 + (wr << 6) + (m << 4) + (lq << 2);
#pragma unroll
    for (int n = 0; n < 8; ++n) {
      int pid = (wp << 7) + (n << 4) + l15;
      int h = h0 + (pid >> 5), w = w0 + (pid & 31);
#pragma unroll
      for (int q = 0; q < 4; ++q) {
        int o = ob + q;
        outb[((long)o << 12) + (h << 6) + w] = acc[m][n][q] + bias[o];
      }
    }
  }
}

extern "C" void kernel_launch(void* const* d_in, const int* in_sizes, int n_in,
                              void* d_out, int out_size, void* d_ws, size_t ws_size,
                              hipStream_t stream) {
  const float* imgs = (const float*)d_in[0];
  const float* w_embs = (const float*)d_in[1];
  const float* cw = (const float*)d_in[2];
  const float* bias = (const float*)d_in[3];
  const float* style_W = (const float*)d_in[4];
  const float* style_b = (const float*)d_in[5];
  float* out = (float*)d_out;

  char* ws = (char*)d_ws;
  float* style = (float*)(ws);                          // 32 KB
  float* rnorm = (float*)(ws + (32 << 10));             // 32 KB
  float* wsq = (float*)(ws + (64 << 10));               // 1 MB
  __bf16* wt = (__bf16*)(ws + (64 << 10) + (1 << 20));  // 75,497,472 B
  __bf16* xpad = (__bf16*)(ws + (64 << 10) + (1 << 20) + 75497472);  // 71,368,704 B
  size_t need = (size_t)(64 << 10) + (1 << 20) + 75497472ull + 71368704ull;
  if (ws_size < need) return;  // leaves d_out poisoned -> visible failure mode

  k_style<<<2048, 256, 0, stream>>>(w_embs, style_W, style_b, style);
  k_wsq<<<1024, 256, 0, stream>>>(cw, wsq);
  k_rnorm<<<2048, 256, 0, stream>>>(style, wsq, rnorm);
  k_wt<<<16384, 256, 0, stream>>>(cw, style, rnorm, wt);
  k_xpad<<<273, 256, 0, stream>>>(imgs, xpad);
  k_conv<<<1024, 256, 0, stream>>>(xpad, wt, bias, out);
}